// Round 5
// baseline (220.636 us; speedup 1.0000x reference)
//
#include <hip/hip_runtime.h>
#include <hip/hip_bf16.h>

#define NUM_B 8
#define SEQ 1024
#define DIM 768
#define NH 12
#define DH 64

typedef __attribute__((ext_vector_type(8))) short bf16x8;
typedef __attribute__((ext_vector_type(4))) float floatx4;
typedef __attribute__((ext_vector_type(4))) unsigned short ushortx4;
typedef __attribute__((ext_vector_type(8))) unsigned short ushortx8;

__device__ __forceinline__ unsigned short f2bf(float f) {
  unsigned u = __float_as_uint(f);
  u += 0x7FFFu + ((u >> 16) & 1u);   // round-to-nearest-even
  return (unsigned short)(u >> 16);
}

// async global->LDS, 16B per lane; LDS dest = wave-uniform base + lane*16
#define GLOAD16(g, l) __builtin_amdgcn_global_load_lds( \
    (const __attribute__((address_space(1))) unsigned int*)(g), \
    (__attribute__((address_space(3))) unsigned int*)(l), 16, 0, 0)

// ---------------- one-shot fp32 -> bf16 conversion (x, Wk, Wo) -------------
__global__ __launch_bounds__(256) void convert_kernel(
    const float* __restrict__ x, const float* __restrict__ Wk,
    const float* __restrict__ Wo, unsigned short* __restrict__ xb,
    unsigned short* __restrict__ Wkb, unsigned short* __restrict__ Wob)
{
  const int NX4 = (8192 * 768) / 4;
  const int NW4 = (768 * 768) / 4;
  int i = blockIdx.x * 256 + threadIdx.x;
  const float* s; unsigned short* d; int off;
  if (i < NX4)            { s = x;  d = xb;  off = i; }
  else if (i < NX4 + NW4) { s = Wk; d = Wkb; off = i - NX4; }
  else                    { s = Wo; d = Wob; off = i - NX4 - NW4; }
  float4 v = ((const float4*)s)[off];
  ushortx4 h;
  h.x = f2bf(v.x); h.y = f2bf(v.y); h.z = f2bf(v.z); h.w = f2bf(v.w);
  ((ushortx4*)d)[off] = h;
}

// ---------------- K projection + fused transpose ---------------------------
// 64(M) x 128(N), BK=64, dbuf swizzled global_load_lds, grid 768 (3/CU).
__global__ __launch_bounds__(256) void proj_k_kernel(
    const unsigned short* __restrict__ xb, const unsigned short* __restrict__ Wkb,
    const float* __restrict__ bk, unsigned short* __restrict__ Kbh,
    unsigned short* __restrict__ KbhT)
{
  __shared__ __align__(16) unsigned short smem[24576];   // 48 KB (2 x 24 KB)
  const int tid = threadIdx.x;
  const int lane = tid & 63;
  const int w = tid >> 6;
  const int wr = w >> 1, wc = w & 1;
  const int quad = lane >> 4, r16 = lane & 15;
  const int rs = r16 & 7;
  const int m0 = blockIdx.x * 64, n0 = blockIdx.y * 128;
  const int wbase = (tid & ~63);

  floatx4 acc[2][4] = {};

  auto stage = [&](int kt, int buf) {
    unsigned short* As = smem + buf * 12288;
    unsigned short* Bs = As + 4096;
#pragma unroll
    for (int i = 0; i < 2; ++i) {
      int c = tid + i * 256;
      int row = c >> 3, g = (c & 7) ^ (row & 7);
      GLOAD16(xb + (size_t)(m0 + row) * DIM + kt + g * 8,
              As + (size_t)(wbase + i * 256) * 8);
    }
#pragma unroll
    for (int i = 0; i < 4; ++i) {
      int c = tid + i * 256;
      int row = c >> 3, g = (c & 7) ^ (row & 7);
      GLOAD16(Wkb + (size_t)(n0 + row) * DIM + kt + g * 8,
              Bs + (size_t)(wbase + i * 256) * 8);
    }
  };

  stage(0, 0);
  int buf = 0;
  for (int it = 0; it < 12; ++it) {
    __syncthreads();
    if (it + 1 < 12) stage((it + 1) * 64, buf ^ 1);
    const unsigned short* As = smem + buf * 12288;
    const unsigned short* Bs = As + 4096;
    bf16x8 af[2][2], bfm[4][2];
#pragma unroll
    for (int mi = 0; mi < 2; ++mi)
#pragma unroll
      for (int kc = 0; kc < 2; ++kc)
        af[mi][kc] = *(const bf16x8*)&As[(wr * 32 + mi * 16 + r16) * 64 + ((kc * 4 + quad) ^ rs) * 8];
#pragma unroll
    for (int ni = 0; ni < 4; ++ni)
#pragma unroll
      for (int kc = 0; kc < 2; ++kc)
        bfm[ni][kc] = *(const bf16x8*)&Bs[(wc * 64 + ni * 16 + r16) * 64 + ((kc * 4 + quad) ^ rs) * 8];
#pragma unroll
    for (int mi = 0; mi < 2; ++mi)
#pragma unroll
      for (int ni = 0; ni < 4; ++ni) {
        acc[mi][ni] = __builtin_amdgcn_mfma_f32_16x16x32_bf16(af[mi][0], bfm[ni][0], acc[mi][ni], 0, 0, 0);
        acc[mi][ni] = __builtin_amdgcn_mfma_f32_16x16x32_bf16(af[mi][1], bfm[ni][1], acc[mi][ni], 0, 0, 0);
      }
    buf ^= 1;
  }

  __syncthreads();                       // reuse smem as Ct [128 n][72]
  unsigned short* Ct = smem;
  const int bb = m0 >> 10, l0 = m0 & 1023;
#pragma unroll
  for (int mi = 0; mi < 2; ++mi)
#pragma unroll
    for (int ni = 0; ni < 4; ++ni) {
      int col = n0 + wc * 64 + ni * 16 + r16;   // j = h*64+dh
      float bias = bk[col];
      int hh = col >> 6, dd = col & 63;
      ushortx4 pk;
#pragma unroll
      for (int r = 0; r < 4; ++r) {
        int mrow = wr * 32 + mi * 16 + quad * 4 + r;
        unsigned short us = f2bf(acc[mi][ni][r] + bias);
        Kbh[((size_t)(bb * NH + hh) * SEQ + l0 + mrow) * DH + dd] = us;
        pk[r] = us;
      }
      *(ushortx4*)&Ct[(wc * 64 + ni * 16 + r16) * 72 + wr * 32 + mi * 16 + quad * 4] = pk;
    }
  __syncthreads();
#pragma unroll
  for (int i = 0; i < 4; ++i) {
    int c = tid + i * 256;
    int row = c >> 3, ch = c & 7;
    ushortx8 v = *(const ushortx8*)&Ct[row * 72 + ch * 8];
    int j = n0 + row;
    int hh = j >> 6, dd = j & 63;
    *(ushortx8*)&KbhT[((size_t)(bb * NH + hh) * DH + dd) * SEQ + l0 + ch * 8] = v;
  }
}

// ---------------- fused attention ------------------------------------------
// 1-D grid 768, 512 threads. 128 q-rows/block, 8 waves x 16 q.
// XCD-aware decode: the 8 q-tiles sharing one bh's K/KT land on the SAME XCD
// (linear%8 == bh%8) -> K/KT served from that XCD's L2 (3 MB working set).
// CHANGE vs R2: the Ks LDS tile is GONE. QK's K-fragments are loaded
// directly from global (L2-resident) into registers: per-CU LDS reads drop
// 432 -> 240 b128 per iteration (every wave was re-reading the whole Ks
// tile), staging halves, LDS 49.5 KB -> 33.5 KB. KTs (V^T) stays LDS-staged
// with the XOR swizzle; Ps hand-off is the R2-verified LDS path.
__global__ __launch_bounds__(512) void attn_kernel(
    const unsigned short* __restrict__ Kbh, const unsigned short* __restrict__ KbhT,
    const int* __restrict__ mask, unsigned short* __restrict__ wV)
{
  __shared__ __align__(16) unsigned short smem[17152];   // 33.5 KB
  // [0,8192): KTs dbuf (2 x 8 KB); [8192,16896): Ps [128][68]; then rsum f32[128]
  unsigned short* Ps = smem + 8192;
  float* rsum = (float*)&smem[16896];

  const int tid = threadIdx.x;
  const int lane = tid & 63;
  const int w = tid >> 6;                // 0..7
  const int quad = lane >> 4, r16 = lane & 15;
  const int rs = r16 & 7;
  // XCD-aware bijective decode (XCD = linear%8 round-robin assumption):
  const int Lb = blockIdx.x;
  const int qt = (Lb >> 3) & 7;
  const int bh = (Lb >> 6) * 8 + (Lb & 7);
  const int b = bh / NH, h = bh % NH;
  const unsigned short* Kb  = Kbh  + (size_t)bh * SEQ * DH;
  const unsigned short* KbT = KbhT + (size_t)bh * DH * SEQ;
  const int q0 = qt * 128;
  const int qw = w * 16;                 // wave's 16-q range within tile
  const int wbase = (tid & ~63);
  // 1/sqrt(768) * log2(e): exp(x*s) == exp2(x*s*log2e)
  const float SCALE2 = 0.036084391824351615f * 1.4426950408889634f;

  // mask folded into scale: masked row -> Q=0 -> St=0 -> p=1 (uniform softmax)
  const float scm = (mask[b * SEQ + q0 + qw + r16] != 0) ? SCALE2 : 0.0f;

  // Q fragments, pre-scaled by scm in bf16 (one-time VALU)
  bf16x8 aq[2];
#pragma unroll
  for (int kc = 0; kc < 2; ++kc) {
    bf16x8 v = *(const bf16x8*)(Kb + (size_t)(q0 + qw + r16) * DH + kc * 32 + quad * 8);
    ushortx8 u; __builtin_memcpy(&u, &v, 16);
    ushortx8 o;
#pragma unroll
    for (int j = 0; j < 8; j += 2) {
      float f0 = __uint_as_float(((unsigned)u[j]) << 16) * scm;
      float f1 = __uint_as_float(((unsigned)u[j + 1]) << 16) * scm;
      __hip_bfloat162 hh = __float22bfloat162_rn(make_float2(f0, f1));
      unsigned hu; __builtin_memcpy(&hu, &hh, 4);
      o[j] = (unsigned short)(hu & 0xffffu);
      o[j + 1] = (unsigned short)(hu >> 16);
    }
    __builtin_memcpy(&aq[kc], &o, 16);
  }

  floatx4 accO[4] = {};
  float psum = 0.0f;

  auto stage = [&](int kt, int buf) {
    unsigned short* KTs = smem + buf * 4096;
    // 512 threads x 16B = one 64x64 bf16 tile, single pass
    int row = tid >> 3, g = (tid & 7) ^ (row & 7);
    GLOAD16(KbT + (size_t)row * SEQ + kt + g * 8,
            KTs + (size_t)wbase * 8);
  };

  stage(0, 0);
  int buf = 0;
  for (int it = 0; it < SEQ / 64; ++it) {
    __syncthreads();
    if (it + 1 < SEQ / 64) stage((it + 1) * 64, buf ^ 1);
    const unsigned short* KTs = smem + buf * 4096;
    const unsigned short* Kit = Kb + (size_t)it * 64 * DH;

    // St[key][q] = K (Q*scm)^T ; A = K-frag direct from global (L2-hit),
    // B = aq (registers). Zero LDS reads in this phase.
    floatx4 St[4] = {};
    __builtin_amdgcn_s_setprio(1);
#pragma unroll
    for (int kt = 0; kt < 4; ++kt) {
      const unsigned short* krow = Kit + (size_t)(kt * 16 + r16) * DH;
      bf16x8 k0 = *(const bf16x8*)(krow + quad * 8);
      bf16x8 k1 = *(const bf16x8*)(krow + 32 + quad * 8);
      St[kt] = __builtin_amdgcn_mfma_f32_16x16x32_bf16(k0, aq[0], St[kt], 0, 0, 0);
      St[kt] = __builtin_amdgcn_mfma_f32_16x16x32_bf16(k1, aq[1], St[kt], 0, 0, 0);
    }
    __builtin_amdgcn_s_setprio(0);

    // P: lane holds keys kt*16+quad*4+{0..3} for q = qw+r16
    // -> exp2 (pre-scaled), packed cvt, ONE b64 LDS write per kt
    {
      int prow = (qw + r16) * 68 + quad * 4;
#pragma unroll
      for (int kt = 0; kt < 4; ++kt) {
        float p0 = __builtin_amdgcn_exp2f(St[kt][0]);
        float p1 = __builtin_amdgcn_exp2f(St[kt][1]);
        float p2 = __builtin_amdgcn_exp2f(St[kt][2]);
        float p3 = __builtin_amdgcn_exp2f(St[kt][3]);
        psum += (p0 + p1) + (p2 + p3);
        __hip_bfloat162 lo = __float22bfloat162_rn(make_float2(p0, p1));
        __hip_bfloat162 hi = __float22bfloat162_rn(make_float2(p2, p3));
        unsigned u0, u1;
        __builtin_memcpy(&u0, &lo, 4);
        __builtin_memcpy(&u1, &hi, 4);
        *(uint2*)&Ps[prow + kt * 16] = make_uint2(u0, u1);
      }
    }

    // O += P V (same-wave LDS RAW on Ps; V^T tile from KTs)
    bf16x8 ap[2];
#pragma unroll
    for (int kc = 0; kc < 2; ++kc)
      ap[kc] = *(const bf16x8*)&Ps[(qw + r16) * 68 + kc * 32 + quad * 8];
    __builtin_amdgcn_s_setprio(1);
#pragma unroll
    for (int ni = 0; ni < 4; ++ni) {
      int rb = (ni * 16 + r16) * 64;
      bf16x8 v0 = *(const bf16x8*)&KTs[rb + ((quad) ^ rs) * 8];
      bf16x8 v1 = *(const bf16x8*)&KTs[rb + ((4 + quad) ^ rs) * 8];
      accO[ni] = __builtin_amdgcn_mfma_f32_16x16x32_bf16(ap[0], v0, accO[ni], 0, 0, 0);
      accO[ni] = __builtin_amdgcn_mfma_f32_16x16x32_bf16(ap[1], v1, accO[ni], 0, 0, 0);
    }
    __builtin_amdgcn_s_setprio(0);
    buf ^= 1;
  }

  // psum lives at q = qw+r16 (quad-partial): reduce over quads, then
  // LDS hop to re-align with the O epilogue's q = quad*4+r layout.
  {
    float s = psum;
    s += __shfl_xor(s, 16);
    s += __shfl_xor(s, 32);
    if (quad == 0) rsum[qw + r16] = s;
  }
  // same-wave DS in-order: reads below see the writes above (own q-range only)
  float rinv[4];
#pragma unroll
  for (int r = 0; r < 4; ++r)
    rinv[r] = 1.0f / rsum[qw + quad * 4 + r];

#pragma unroll
  for (int ni = 0; ni < 4; ++ni)
#pragma unroll
    for (int r = 0; r < 4; ++r) {
      int l = q0 + qw + quad * 4 + r;
      int col = h * DH + ni * 16 + r16;
      wV[(size_t)(b * SEQ + l) * DIM + col] = f2bf(accO[ni][r] * rinv[r]);
    }
}

// ---------------- output projection: out = wV @ Wo^T + bo (fp32) -----------
__global__ __launch_bounds__(256) void proj_o_kernel(
    const unsigned short* __restrict__ wVb, const unsigned short* __restrict__ Wob,
    const float* __restrict__ bo, float* __restrict__ out)
{
  __shared__ __align__(16) unsigned short smem[24576];   // 48 KB
  const int tid = threadIdx.x;
  const int lane = tid & 63;
  const int w = tid >> 6;
  const int wr = w >> 1, wc = w & 1;
  const int quad = lane >> 4, r16 = lane & 15;
  const int rs = r16 & 7;
  const int m0 = blockIdx.x * 64, n0 = blockIdx.y * 128;
  const int wbase = (tid & ~63);

  floatx4 acc[2][4] = {};

  auto stage = [&](int kt, int buf) {
    unsigned short* As = smem + buf * 12288;
    unsigned short* Bs = As + 4096;
#pragma unroll
    for (int i = 0; i < 2; ++i) {
      int c = tid + i * 256;
      int row = c >> 3, g = (c & 7) ^ (row & 7);
      GLOAD16(wVb + (size_t)(m0 + row) * DIM + kt + g * 8,
              As + (size_t)(wbase + i * 256) * 8);
    }
#pragma unroll
    for (int i = 0; i < 4; ++i) {
      int c = tid + i * 256;
      int row = c >> 3, g = (c & 7) ^ (row & 7);
      GLOAD16(Wob + (size_t)(n0 + row) * DIM + kt + g * 8,
              Bs + (size_t)(wbase + i * 256) * 8);
    }
  };

  stage(0, 0);
  int buf = 0;
  for (int it = 0; it < 12; ++it) {
    __syncthreads();
    if (it + 1 < 12) stage((it + 1) * 64, buf ^ 1);
    const unsigned short* As = smem + buf * 12288;
    const unsigned short* Bs = As + 4096;
    bf16x8 af[2][2], bfm[4][2];
#pragma unroll
    for (int mi = 0; mi < 2; ++mi)
#pragma unroll
      for (int kc = 0; kc < 2; ++kc)
        af[mi][kc] = *(const bf16x8*)&As[(wr * 32 + mi * 16 + r16) * 64 + ((kc * 4 + quad) ^ rs) * 8];
#pragma unroll
    for (int ni = 0; ni < 4; ++ni)
#pragma unroll
      for (int kc = 0; kc < 2; ++kc)
        bfm[ni][kc] = *(const bf16x8*)&Bs[(wc * 64 + ni * 16 + r16) * 64 + ((kc * 4 + quad) ^ rs) * 8];
#pragma unroll
    for (int mi = 0; mi < 2; ++mi)
#pragma unroll
      for (int ni = 0; ni < 4; ++ni) {
        acc[mi][ni] = __builtin_amdgcn_mfma_f32_16x16x32_bf16(af[mi][0], bfm[ni][0], acc[mi][ni], 0, 0, 0);
        acc[mi][ni] = __builtin_amdgcn_mfma_f32_16x16x32_bf16(af[mi][1], bfm[ni][1], acc[mi][ni], 0, 0, 0);
      }
    buf ^= 1;
  }

#pragma unroll
  for (int mi = 0; mi < 2; ++mi)
#pragma unroll
    for (int ni = 0; ni < 4; ++ni) {
      int col = n0 + wc * 64 + ni * 16 + r16;
      float bias = bo[col];
#pragma unroll
      for (int r = 0; r < 4; ++r) {
        int row = m0 + wr * 32 + mi * 16 + quad * 4 + r;
        out[(size_t)row * DIM + col] = acc[mi][ni][r] + bias;
      }
    }
}

extern "C" void kernel_launch(void* const* d_in, const int* in_sizes, int n_in,
                              void* d_out, int out_size, void* d_ws, size_t ws_size,
                              hipStream_t stream) {
  // inputs: x, attention_mask, Wq, bq, Wk, bk, Wv, bv, Wo, bo  (Q dead; V==K)
  const float* x  = (const float*)d_in[0];
  const int* mask = (const int*)d_in[1];
  const float* Wk = (const float*)d_in[4];
  const float* bk = (const float*)d_in[5];
  const float* Wo = (const float*)d_in[8];
  const float* bo = (const float*)d_in[9];
  float* out = (float*)d_out;

  unsigned short* p = (unsigned short*)d_ws;
  unsigned short* xb   = p;  p += (size_t)8192 * 768;
  unsigned short* Wkb  = p;  p += (size_t)768 * 768;
  unsigned short* Wob  = p;  p += (size_t)768 * 768;
  unsigned short* Kbh  = p;  p += (size_t)NUM_B * NH * SEQ * DH;
  unsigned short* KbhT = p;  p += (size_t)NUM_B * NH * SEQ * DH;
  unsigned short* wVb  = p;  // [8192][768]

  convert_kernel<<<7296, 256, 0, stream>>>(x, Wk, Wo, xb, Wkb, Wob);
  proj_k_kernel<<<dim3(128, 6), 256, 0, stream>>>(xb, Wkb, bk, Kbh, KbhT);
  attn_kernel<<<768, 512, 0, stream>>>(Kbh, KbhT, mask, wVb);
  proj_o_kernel<<<dim3(128, 6), 256, 0, stream>>>(wVb, Wob, bo, out);
}

// Round 6
// 183.862 us; speedup vs baseline: 1.2000x; 1.2000x over previous
//
#include <hip/hip_runtime.h>
#include <hip/hip_bf16.h>

#define NUM_B 8
#define SEQ 1024
#define DIM 768
#define NH 12
#define DH 64

typedef __attribute__((ext_vector_type(8))) short bf16x8;
typedef __attribute__((ext_vector_type(4))) float floatx4;
typedef __attribute__((ext_vector_type(4))) unsigned short ushortx4;
typedef __attribute__((ext_vector_type(8))) unsigned short ushortx8;

__device__ __forceinline__ unsigned short f2bf(float f) {
  unsigned u = __float_as_uint(f);
  u += 0x7FFFu + ((u >> 16) & 1u);   // round-to-nearest-even
  return (unsigned short)(u >> 16);
}

// async global->LDS, 16B per lane; LDS dest = wave-uniform base + lane*16
#define GLOAD16(g, l) __builtin_amdgcn_global_load_lds( \
    (const __attribute__((address_space(1))) unsigned int*)(g), \
    (__attribute__((address_space(3))) unsigned int*)(l), 16, 0, 0)

// ---------------- one-shot fp32 -> bf16 conversion (x, Wk, Wo) -------------
__global__ __launch_bounds__(256) void convert_kernel(
    const float* __restrict__ x, const float* __restrict__ Wk,
    const float* __restrict__ Wo, unsigned short* __restrict__ xb,
    unsigned short* __restrict__ Wkb, unsigned short* __restrict__ Wob)
{
  const int NX4 = (8192 * 768) / 4;
  const int NW4 = (768 * 768) / 4;
  int i = blockIdx.x * 256 + threadIdx.x;
  const float* s; unsigned short* d; int off;
  if (i < NX4)            { s = x;  d = xb;  off = i; }
  else if (i < NX4 + NW4) { s = Wk; d = Wkb; off = i - NX4; }
  else                    { s = Wo; d = Wob; off = i - NX4 - NW4; }
  float4 v = ((const float4*)s)[off];
  ushortx4 h;
  h.x = f2bf(v.x); h.y = f2bf(v.y); h.z = f2bf(v.z); h.w = f2bf(v.w);
  ((ushortx4*)d)[off] = h;
}

// ---------------- K projection + fused transpose ---------------------------
// 64(M) x 128(N), BK=64, dbuf swizzled global_load_lds, grid 768 (3/CU).
__global__ __launch_bounds__(256) void proj_k_kernel(
    const unsigned short* __restrict__ xb, const unsigned short* __restrict__ Wkb,
    const float* __restrict__ bk, unsigned short* __restrict__ Kbh,
    unsigned short* __restrict__ KbhT)
{
  __shared__ __align__(16) unsigned short smem[24576];   // 48 KB (2 x 24 KB)
  const int tid = threadIdx.x;
  const int lane = tid & 63;
  const int w = tid >> 6;
  const int wr = w >> 1, wc = w & 1;
  const int quad = lane >> 4, r16 = lane & 15;
  const int rs = r16 & 7;
  const int m0 = blockIdx.x * 64, n0 = blockIdx.y * 128;
  const int wbase = (tid & ~63);

  floatx4 acc[2][4] = {};

  auto stage = [&](int kt, int buf) {
    unsigned short* As = smem + buf * 12288;
    unsigned short* Bs = As + 4096;
#pragma unroll
    for (int i = 0; i < 2; ++i) {
      int c = tid + i * 256;
      int row = c >> 3, g = (c & 7) ^ (row & 7);
      GLOAD16(xb + (size_t)(m0 + row) * DIM + kt + g * 8,
              As + (size_t)(wbase + i * 256) * 8);
    }
#pragma unroll
    for (int i = 0; i < 4; ++i) {
      int c = tid + i * 256;
      int row = c >> 3, g = (c & 7) ^ (row & 7);
      GLOAD16(Wkb + (size_t)(n0 + row) * DIM + kt + g * 8,
              Bs + (size_t)(wbase + i * 256) * 8);
    }
  };

  stage(0, 0);
  int buf = 0;
  for (int it = 0; it < 12; ++it) {
    __syncthreads();
    if (it + 1 < 12) stage((it + 1) * 64, buf ^ 1);
    const unsigned short* As = smem + buf * 12288;
    const unsigned short* Bs = As + 4096;
    bf16x8 af[2][2], bfm[4][2];
#pragma unroll
    for (int mi = 0; mi < 2; ++mi)
#pragma unroll
      for (int kc = 0; kc < 2; ++kc)
        af[mi][kc] = *(const bf16x8*)&As[(wr * 32 + mi * 16 + r16) * 64 + ((kc * 4 + quad) ^ rs) * 8];
#pragma unroll
    for (int ni = 0; ni < 4; ++ni)
#pragma unroll
      for (int kc = 0; kc < 2; ++kc)
        bfm[ni][kc] = *(const bf16x8*)&Bs[(wc * 64 + ni * 16 + r16) * 64 + ((kc * 4 + quad) ^ rs) * 8];
#pragma unroll
    for (int mi = 0; mi < 2; ++mi)
#pragma unroll
      for (int ni = 0; ni < 4; ++ni) {
        acc[mi][ni] = __builtin_amdgcn_mfma_f32_16x16x32_bf16(af[mi][0], bfm[ni][0], acc[mi][ni], 0, 0, 0);
        acc[mi][ni] = __builtin_amdgcn_mfma_f32_16x16x32_bf16(af[mi][1], bfm[ni][1], acc[mi][ni], 0, 0, 0);
      }
    buf ^= 1;
  }

  __syncthreads();                       // reuse smem as Ct [128 n][72]
  unsigned short* Ct = smem;
  const int bb = m0 >> 10, l0 = m0 & 1023;
#pragma unroll
  for (int mi = 0; mi < 2; ++mi)
#pragma unroll
    for (int ni = 0; ni < 4; ++ni) {
      int col = n0 + wc * 64 + ni * 16 + r16;   // j = h*64+dh
      float bias = bk[col];
      int hh = col >> 6, dd = col & 63;
      ushortx4 pk;
#pragma unroll
      for (int r = 0; r < 4; ++r) {
        int mrow = wr * 32 + mi * 16 + quad * 4 + r;
        unsigned short us = f2bf(acc[mi][ni][r] + bias);
        Kbh[((size_t)(bb * NH + hh) * SEQ + l0 + mrow) * DH + dd] = us;
        pk[r] = us;
      }
      *(ushortx4*)&Ct[(wc * 64 + ni * 16 + r16) * 72 + wr * 32 + mi * 16 + quad * 4] = pk;
    }
  __syncthreads();
#pragma unroll
  for (int i = 0; i < 4; ++i) {
    int c = tid + i * 256;
    int row = c >> 3, ch = c & 7;
    ushortx8 v = *(const ushortx8*)&Ct[row * 72 + ch * 8];
    int j = n0 + row;
    int hh = j >> 6, dd = j & 63;
    *(ushortx8*)&KbhT[((size_t)(bb * NH + hh) * DH + dd) * SEQ + l0 + ch * 8] = v;
  }
}

// ---------------- fused attention ------------------------------------------
// 1-D grid 384, 512 threads. 256 q-rows/block, 8 waves x 32 q.
// LDS-traffic fix: the shared K/V fragment reads are a fixed 256 B/lane/tile
// regardless of q-per-wave, so total LDS reads scale as 1/(q-per-wave).
// 32 q/wave (R0's verified per-wave body) halves read traffic vs 16 q/wave;
// 8 waves/block at 67 KB LDS gives 2 blocks/CU = 16 waves/CU for latency.
// XCD decode: 4 q-tiles of each bh on one XCD (Lb%8 == bh%8), K/KT L2-resident.
__global__ __launch_bounds__(512) void attn_kernel(
    const unsigned short* __restrict__ Kbh, const unsigned short* __restrict__ KbhT,
    const int* __restrict__ mask, unsigned short* __restrict__ wV)
{
  __shared__ __align__(16) unsigned short smem[34304];   // 67 KB
  // [0,32768)B: Ks/KTs dbuf; [32768,67584)B: Ps [256][68]; [67584,): rsum f32[256]
  unsigned short* Ps = smem + 16384;
  float* rsum = (float*)&smem[33792];

  const int tid = threadIdx.x;
  const int lane = tid & 63;
  const int w = tid >> 6;                // 0..7
  const int quad = lane >> 4, r16 = lane & 15;
  const int rs = r16 & 7;
  // XCD-aware bijective decode for grid 384 (XCD = linear%8 round-robin):
  const int Lb = blockIdx.x;
  const int qt = (Lb >> 3) & 3;
  const int bh = (Lb >> 5) * 8 + (Lb & 7);
  const int b = bh / NH, h = bh % NH;
  const unsigned short* Kb  = Kbh  + (size_t)bh * SEQ * DH;
  const unsigned short* KbT = KbhT + (size_t)bh * DH * SEQ;
  const int q0 = qt * 256;
  const int qw = w * 32;                 // wave's 32-q range within tile
  const int wbase = (tid & ~63);
  // 1/sqrt(768) * log2(e): exp(x*s) == exp2(x*s*log2e)
  const float SCALE2 = 0.036084391824351615f * 1.4426950408889634f;

  // mask folded into scale: masked row -> arg 0 -> p=1 (uniform softmax)
  float scm[2];
#pragma unroll
  for (int nt = 0; nt < 2; ++nt)
    scm[nt] = (mask[b * SEQ + q0 + qw + nt * 16 + r16] != 0) ? SCALE2 : 0.0f;

  // Q fragments; B-operand layout == A-operand layout per-lane.
  bf16x8 aq[2][2];
#pragma unroll
  for (int nt = 0; nt < 2; ++nt)
#pragma unroll
    for (int kc = 0; kc < 2; ++kc)
      aq[nt][kc] = *(const bf16x8*)(Kb + (size_t)(q0 + qw + nt * 16 + r16) * DH + kc * 32 + quad * 8);

  floatx4 accO[2][4] = {};
  float psum[2] = {};

  auto stage = [&](int kt, int buf) {
    unsigned short* Ks  = smem + buf * 4096;
    unsigned short* KTs = smem + 8192 + buf * 4096;
    // 512 threads x 16B = one 64x64 bf16 tile each, single pass
    int row = tid >> 3, g = (tid & 7) ^ (row & 7);
    GLOAD16(Kb + (size_t)(kt + row) * DH + g * 8,
            Ks + (size_t)wbase * 8);
    GLOAD16(KbT + (size_t)row * SEQ + kt + g * 8,
            KTs + (size_t)wbase * 8);
  };

  stage(0, 0);
  int buf = 0;
  for (int it = 0; it < SEQ / 64; ++it) {
    __syncthreads();
    if (it + 1 < SEQ / 64) stage((it + 1) * 64, buf ^ 1);
    const unsigned short* Ks  = smem + buf * 4096;
    const unsigned short* KTs = smem + 8192 + buf * 4096;

    // St[key][q] = K Q^T ; A = K-frag (m=key), B = aq (n=q). One k0/k1 read
    // pair feeds 4 MFMAs (2 nt x 2 kc): the traffic amortization.
    floatx4 St[4][2] = {};
    __builtin_amdgcn_s_setprio(1);
#pragma unroll
    for (int kt = 0; kt < 4; ++kt) {
      int rb = (kt * 16 + r16) * 64;
      bf16x8 k0 = *(const bf16x8*)&Ks[rb + ((quad) ^ rs) * 8];
      bf16x8 k1 = *(const bf16x8*)&Ks[rb + ((4 + quad) ^ rs) * 8];
#pragma unroll
      for (int nt = 0; nt < 2; ++nt) {
        St[kt][nt] = __builtin_amdgcn_mfma_f32_16x16x32_bf16(k0, aq[nt][0], St[kt][nt], 0, 0, 0);
        St[kt][nt] = __builtin_amdgcn_mfma_f32_16x16x32_bf16(k1, aq[nt][1], St[kt][nt], 0, 0, 0);
      }
    }
    __builtin_amdgcn_s_setprio(0);

    // P: lane holds keys kt*16+quad*4+{0..3} for q = qw+nt*16+r16
    // -> exp2, packed cvt, ONE b64 LDS write per (nt,kt)
#pragma unroll
    for (int nt = 0; nt < 2; ++nt) {
      float sc = scm[nt];
      int prow = (qw + nt * 16 + r16) * 68 + quad * 4;
#pragma unroll
      for (int kt = 0; kt < 4; ++kt) {
        float p0 = __builtin_amdgcn_exp2f(St[kt][nt][0] * sc);
        float p1 = __builtin_amdgcn_exp2f(St[kt][nt][1] * sc);
        float p2 = __builtin_amdgcn_exp2f(St[kt][nt][2] * sc);
        float p3 = __builtin_amdgcn_exp2f(St[kt][nt][3] * sc);
        psum[nt] += (p0 + p1) + (p2 + p3);
        __hip_bfloat162 lo = __float22bfloat162_rn(make_float2(p0, p1));
        __hip_bfloat162 hi = __float22bfloat162_rn(make_float2(p2, p3));
        unsigned u0, u1;
        __builtin_memcpy(&u0, &lo, 4);
        __builtin_memcpy(&u1, &hi, 4);
        *(uint2*)&Ps[prow + kt * 16] = make_uint2(u0, u1);
      }
    }

    // O += P V (same-wave LDS RAW on Ps; V^T tile from KTs). One v0/v1 read
    // pair feeds 4 MFMAs (2 mi x 2 kc).
    bf16x8 ap[2][2];
#pragma unroll
    for (int mi = 0; mi < 2; ++mi)
#pragma unroll
      for (int kc = 0; kc < 2; ++kc)
        ap[mi][kc] = *(const bf16x8*)&Ps[(qw + mi * 16 + r16) * 68 + kc * 32 + quad * 8];
    __builtin_amdgcn_s_setprio(1);
#pragma unroll
    for (int ni = 0; ni < 4; ++ni) {
      int rb = (ni * 16 + r16) * 64;
      bf16x8 v0 = *(const bf16x8*)&KTs[rb + ((quad) ^ rs) * 8];
      bf16x8 v1 = *(const bf16x8*)&KTs[rb + ((4 + quad) ^ rs) * 8];
#pragma unroll
      for (int mi = 0; mi < 2; ++mi) {
        accO[mi][ni] = __builtin_amdgcn_mfma_f32_16x16x32_bf16(ap[mi][0], v0, accO[mi][ni], 0, 0, 0);
        accO[mi][ni] = __builtin_amdgcn_mfma_f32_16x16x32_bf16(ap[mi][1], v1, accO[mi][ni], 0, 0, 0);
      }
    }
    __builtin_amdgcn_s_setprio(0);
    buf ^= 1;
  }

  // psum lives at q = qw+nt*16+r16 (quad-partial): reduce over quads, then
  // LDS hop to re-align with the O epilogue's q = quad*4+r layout.
#pragma unroll
  for (int nt = 0; nt < 2; ++nt) {
    float s = psum[nt];
    s += __shfl_xor(s, 16);
    s += __shfl_xor(s, 32);
    psum[nt] = s;
  }
  if (quad == 0) {
#pragma unroll
    for (int nt = 0; nt < 2; ++nt)
      rsum[qw + nt * 16 + r16] = psum[nt];
  }
  // same-wave DS in-order: reads below see the writes above (own q-range only)
  float rinv[2][4];
#pragma unroll
  for (int mi = 0; mi < 2; ++mi)
#pragma unroll
    for (int r = 0; r < 4; ++r)
      rinv[mi][r] = 1.0f / rsum[qw + mi * 16 + quad * 4 + r];

#pragma unroll
  for (int mi = 0; mi < 2; ++mi)
#pragma unroll
    for (int ni = 0; ni < 4; ++ni)
#pragma unroll
      for (int r = 0; r < 4; ++r) {
        int l = q0 + qw + mi * 16 + quad * 4 + r;
        int col = h * DH + ni * 16 + r16;
        wV[(size_t)(b * SEQ + l) * DIM + col] = f2bf(accO[mi][ni][r] * rinv[mi][r]);
      }
}

// ---------------- output projection: out = wV @ Wo^T + bo (fp32) -----------
__global__ __launch_bounds__(256) void proj_o_kernel(
    const unsigned short* __restrict__ wVb, const unsigned short* __restrict__ Wob,
    const float* __restrict__ bo, float* __restrict__ out)
{
  __shared__ __align__(16) unsigned short smem[24576];   // 48 KB
  const int tid = threadIdx.x;
  const int lane = tid & 63;
  const int w = tid >> 6;
  const int wr = w >> 1, wc = w & 1;
  const int quad = lane >> 4, r16 = lane & 15;
  const int rs = r16 & 7;
  const int m0 = blockIdx.x * 64, n0 = blockIdx.y * 128;
  const int wbase = (tid & ~63);

  floatx4 acc[2][4] = {};

  auto stage = [&](int kt, int buf) {
    unsigned short* As = smem + buf * 12288;
    unsigned short* Bs = As + 4096;
#pragma unroll
    for (int i = 0; i < 2; ++i) {
      int c = tid + i * 256;
      int row = c >> 3, g = (c & 7) ^ (row & 7);
      GLOAD16(wVb + (size_t)(m0 + row) * DIM + kt + g * 8,
              As + (size_t)(wbase + i * 256) * 8);
    }
#pragma unroll
    for (int i = 0; i < 4; ++i) {
      int c = tid + i * 256;
      int row = c >> 3, g = (c & 7) ^ (row & 7);
      GLOAD16(Wob + (size_t)(n0 + row) * DIM + kt + g * 8,
              Bs + (size_t)(wbase + i * 256) * 8);
    }
  };

  stage(0, 0);
  int buf = 0;
  for (int it = 0; it < 12; ++it) {
    __syncthreads();
    if (it + 1 < 12) stage((it + 1) * 64, buf ^ 1);
    const unsigned short* As = smem + buf * 12288;
    const unsigned short* Bs = As + 4096;
    bf16x8 af[2][2], bfm[4][2];
#pragma unroll
    for (int mi = 0; mi < 2; ++mi)
#pragma unroll
      for (int kc = 0; kc < 2; ++kc)
        af[mi][kc] = *(const bf16x8*)&As[(wr * 32 + mi * 16 + r16) * 64 + ((kc * 4 + quad) ^ rs) * 8];
#pragma unroll
    for (int ni = 0; ni < 4; ++ni)
#pragma unroll
      for (int kc = 0; kc < 2; ++kc)
        bfm[ni][kc] = *(const bf16x8*)&Bs[(wc * 64 + ni * 16 + r16) * 64 + ((kc * 4 + quad) ^ rs) * 8];
#pragma unroll
    for (int mi = 0; mi < 2; ++mi)
#pragma unroll
      for (int ni = 0; ni < 4; ++ni) {
        acc[mi][ni] = __builtin_amdgcn_mfma_f32_16x16x32_bf16(af[mi][0], bfm[ni][0], acc[mi][ni], 0, 0, 0);
        acc[mi][ni] = __builtin_amdgcn_mfma_f32_16x16x32_bf16(af[mi][1], bfm[ni][1], acc[mi][ni], 0, 0, 0);
      }
    buf ^= 1;
  }

#pragma unroll
  for (int mi = 0; mi < 2; ++mi)
#pragma unroll
    for (int ni = 0; ni < 4; ++ni) {
      int col = n0 + wc * 64 + ni * 16 + r16;
      float bias = bo[col];
#pragma unroll
      for (int r = 0; r < 4; ++r) {
        int row = m0 + wr * 32 + mi * 16 + quad * 4 + r;
        out[(size_t)row * DIM + col] = acc[mi][ni][r] + bias;
      }
    }
}

extern "C" void kernel_launch(void* const* d_in, const int* in_sizes, int n_in,
                              void* d_out, int out_size, void* d_ws, size_t ws_size,
                              hipStream_t stream) {
  // inputs: x, attention_mask, Wq, bq, Wk, bk, Wv, bv, Wo, bo  (Q dead; V==K)
  const float* x  = (const float*)d_in[0];
  const int* mask = (const int*)d_in[1];
  const float* Wk = (const float*)d_in[4];
  const float* bk = (const float*)d_in[5];
  const float* Wo = (const float*)d_in[8];
  const float* bo = (const float*)d_in[9];
  float* out = (float*)d_out;

  unsigned short* p = (unsigned short*)d_ws;
  unsigned short* xb   = p;  p += (size_t)8192 * 768;
  unsigned short* Wkb  = p;  p += (size_t)768 * 768;
  unsigned short* Wob  = p;  p += (size_t)768 * 768;
  unsigned short* Kbh  = p;  p += (size_t)NUM_B * NH * SEQ * DH;
  unsigned short* KbhT = p;  p += (size_t)NUM_B * NH * SEQ * DH;
  unsigned short* wVb  = p;  // [8192][768]

  convert_kernel<<<7296, 256, 0, stream>>>(x, Wk, Wo, xb, Wkb, Wob);
  proj_k_kernel<<<dim3(128, 6), 256, 0, stream>>>(xb, Wkb, bk, Kbh, KbhT);
  attn_kernel<<<384, 512, 0, stream>>>(Kbh, KbhT, mask, wVb);
  proj_o_kernel<<<dim3(128, 6), 256, 0, stream>>>(wVb, Wob, bo, out);
}

// Round 8
// 174.367 us; speedup vs baseline: 1.2654x; 1.0545x over previous
//
#include <hip/hip_runtime.h>
#include <hip/hip_bf16.h>

#define NUM_B 8
#define SEQ 1024
#define DIM 768
#define NH 12
#define DH 64

typedef __attribute__((ext_vector_type(8))) short bf16x8;
typedef __attribute__((ext_vector_type(4))) float floatx4;
typedef __attribute__((ext_vector_type(4))) unsigned short ushortx4;
typedef __attribute__((ext_vector_type(8))) unsigned short ushortx8;

__device__ __forceinline__ unsigned short f2bf(float f) {
  unsigned u = __float_as_uint(f);
  u += 0x7FFFu + ((u >> 16) & 1u);   // round-to-nearest-even
  return (unsigned short)(u >> 16);
}

// async global->LDS, 16B per lane; LDS dest = wave-uniform base + lane*16
#define GLOAD16(g, l) __builtin_amdgcn_global_load_lds( \
    (const __attribute__((address_space(1))) unsigned int*)(g), \
    (__attribute__((address_space(3))) unsigned int*)(l), 16, 0, 0)

// ---------------- one-shot fp32 -> bf16 conversion (x, Wk, Wo) -------------
__global__ __launch_bounds__(256) void convert_kernel(
    const float* __restrict__ x, const float* __restrict__ Wk,
    const float* __restrict__ Wo, unsigned short* __restrict__ xb,
    unsigned short* __restrict__ Wkb, unsigned short* __restrict__ Wob)
{
  const int NX4 = (8192 * 768) / 4;
  const int NW4 = (768 * 768) / 4;
  int i = blockIdx.x * 256 + threadIdx.x;
  const float* s; unsigned short* d; int off;
  if (i < NX4)            { s = x;  d = xb;  off = i; }
  else if (i < NX4 + NW4) { s = Wk; d = Wkb; off = i - NX4; }
  else                    { s = Wo; d = Wob; off = i - NX4 - NW4; }
  float4 v = ((const float4*)s)[off];
  ushortx4 h;
  h.x = f2bf(v.x); h.y = f2bf(v.y); h.z = f2bf(v.z); h.w = f2bf(v.w);
  ((ushortx4*)d)[off] = h;
}

// ---------------- K projection + fused transpose ---------------------------
// 64(M) x 128(N), BK=64, dbuf swizzled global_load_lds, grid 768 (3/CU).
__global__ __launch_bounds__(256) void proj_k_kernel(
    const unsigned short* __restrict__ xb, const unsigned short* __restrict__ Wkb,
    const float* __restrict__ bk, unsigned short* __restrict__ Kbh,
    unsigned short* __restrict__ KbhT)
{
  __shared__ __align__(16) unsigned short smem[24576];   // 48 KB (2 x 24 KB)
  const int tid = threadIdx.x;
  const int lane = tid & 63;
  const int w = tid >> 6;
  const int wr = w >> 1, wc = w & 1;
  const int quad = lane >> 4, r16 = lane & 15;
  const int rs = r16 & 7;
  const int m0 = blockIdx.x * 64, n0 = blockIdx.y * 128;
  const int wbase = (tid & ~63);

  floatx4 acc[2][4] = {};

  auto stage = [&](int kt, int buf) {
    unsigned short* As = smem + buf * 12288;
    unsigned short* Bs = As + 4096;
#pragma unroll
    for (int i = 0; i < 2; ++i) {
      int c = tid + i * 256;
      int row = c >> 3, g = (c & 7) ^ (row & 7);
      GLOAD16(xb + (size_t)(m0 + row) * DIM + kt + g * 8,
              As + (size_t)(wbase + i * 256) * 8);
    }
#pragma unroll
    for (int i = 0; i < 4; ++i) {
      int c = tid + i * 256;
      int row = c >> 3, g = (c & 7) ^ (row & 7);
      GLOAD16(Wkb + (size_t)(n0 + row) * DIM + kt + g * 8,
              Bs + (size_t)(wbase + i * 256) * 8);
    }
  };

  stage(0, 0);
  int buf = 0;
  for (int it = 0; it < 12; ++it) {
    __syncthreads();
    if (it + 1 < 12) stage((it + 1) * 64, buf ^ 1);
    const unsigned short* As = smem + buf * 12288;
    const unsigned short* Bs = As + 4096;
    bf16x8 af[2][2], bfm[4][2];
#pragma unroll
    for (int mi = 0; mi < 2; ++mi)
#pragma unroll
      for (int kc = 0; kc < 2; ++kc)
        af[mi][kc] = *(const bf16x8*)&As[(wr * 32 + mi * 16 + r16) * 64 + ((kc * 4 + quad) ^ rs) * 8];
#pragma unroll
    for (int ni = 0; ni < 4; ++ni)
#pragma unroll
      for (int kc = 0; kc < 2; ++kc)
        bfm[ni][kc] = *(const bf16x8*)&Bs[(wc * 64 + ni * 16 + r16) * 64 + ((kc * 4 + quad) ^ rs) * 8];
#pragma unroll
    for (int mi = 0; mi < 2; ++mi)
#pragma unroll
      for (int ni = 0; ni < 4; ++ni) {
        acc[mi][ni] = __builtin_amdgcn_mfma_f32_16x16x32_bf16(af[mi][0], bfm[ni][0], acc[mi][ni], 0, 0, 0);
        acc[mi][ni] = __builtin_amdgcn_mfma_f32_16x16x32_bf16(af[mi][1], bfm[ni][1], acc[mi][ni], 0, 0, 0);
      }
    buf ^= 1;
  }

  __syncthreads();                       // reuse smem as Ct [128 n][72]
  unsigned short* Ct = smem;
  const int bb = m0 >> 10, l0 = m0 & 1023;
#pragma unroll
  for (int mi = 0; mi < 2; ++mi)
#pragma unroll
    for (int ni = 0; ni < 4; ++ni) {
      int col = n0 + wc * 64 + ni * 16 + r16;   // j = h*64+dh
      float bias = bk[col];
      int hh = col >> 6, dd = col & 63;
      ushortx4 pk;
#pragma unroll
      for (int r = 0; r < 4; ++r) {
        int mrow = wr * 32 + mi * 16 + quad * 4 + r;
        unsigned short us = f2bf(acc[mi][ni][r] + bias);
        Kbh[((size_t)(bb * NH + hh) * SEQ + l0 + mrow) * DH + dd] = us;
        pk[r] = us;
      }
      *(ushortx4*)&Ct[(wc * 64 + ni * 16 + r16) * 72 + wr * 32 + mi * 16 + quad * 4] = pk;
    }
  __syncthreads();
#pragma unroll
  for (int i = 0; i < 4; ++i) {
    int c = tid + i * 256;
    int row = c >> 3, ch = c & 7;
    ushortx8 v = *(const ushortx8*)&Ct[row * 72 + ch * 8];
    int j = n0 + row;
    int hh = j >> 6, dd = j & 63;
    *(ushortx8*)&KbhT[((size_t)(bb * NH + hh) * DH + dd) * SEQ + l0 + ch * 8] = v;
  }
}

// ---------------- fused attention ------------------------------------------
// 1-D grid 768 (3 blocks/CU, balanced), 512 threads. 128 q-rows/block,
// 8 waves = 4 q-groups x 2 KEY-HALVES (split-K). Wave (qg,kh) computes its
// 32 q-rows over keys kh*32..+31 of each 64-key tile: per-wave LDS reads
// drop 18 -> 10 ds_read_b128 per iter (the kernel's dominant pipe), while
// MFMA/exp2 totals are invariant. P stays wave-private (disjoint Ps column
// ranges). Epilogue: kh=1 dumps accO(f32)+psum to LDS, kh=0 reduces,
// divides, stores. Softmax sum is order-free -> exact.
// XCD decode: 8 q-tiles of each bh on one XCD (Lb%8==bh%8), K/KT L2-resident.
__global__ __launch_bounds__(512) void attn_kernel(
    const unsigned short* __restrict__ Kbh, const unsigned short* __restrict__ KbhT,
    const int* __restrict__ mask, unsigned short* __restrict__ wV)
{
  __shared__ __align__(16) unsigned short smem[25600];   // 51.2 KB
  // shorts: [0,16384) Ks/KTs dbuf; [16384,25088) Ps [128][68];
  // [25088,25344) r0 f32[128]; [25344,25600) r1 f32[128].
  // Epilogue reuse: Of f32[128][66] over [0,16896) shorts (after sync).
  unsigned short* Ps = smem + 16384;

  const int tid = threadIdx.x;
  const int lane = tid & 63;
  const int w = tid >> 6;                // 0..7
  const int qg = w >> 1, kh = w & 1;     // q-group / key-half
  const int quad = lane >> 4, r16 = lane & 15;
  const int rs = r16 & 7;
  // XCD-aware bijective decode (XCD = linear%8 round-robin assumption):
  const int Lb = blockIdx.x;
  const int qt = (Lb >> 3) & 7;
  const int bh = (Lb >> 6) * 8 + (Lb & 7);
  const int b = bh / NH, h = bh % NH;
  const unsigned short* Kb  = Kbh  + (size_t)bh * SEQ * DH;
  const unsigned short* KbT = KbhT + (size_t)bh * DH * SEQ;
  const int q0 = qt * 128;
  const int qw = qg * 32;                // q-group's 32-q range within tile
  const int wbase = (tid & ~63);
  // 1/sqrt(768) * log2(e): exp(x*s) == exp2(x*s*log2e)
  const float SCALE2 = 0.036084391824351615f * 1.4426950408889634f;

  // mask folded into scale: masked row -> arg 0 -> p=1 (uniform softmax)
  float scm[2];
#pragma unroll
  for (int nt = 0; nt < 2; ++nt)
    scm[nt] = (mask[b * SEQ + q0 + qw + nt * 16 + r16] != 0) ? SCALE2 : 0.0f;

  // Q fragments (B-operand); both key-halves of a q-group load the same Q.
  bf16x8 aq[2][2];
#pragma unroll
  for (int nt = 0; nt < 2; ++nt)
#pragma unroll
    for (int kc = 0; kc < 2; ++kc)
      aq[nt][kc] = *(const bf16x8*)(Kb + (size_t)(q0 + qw + nt * 16 + r16) * DH + kc * 32 + quad * 8);

  floatx4 accO[2][4] = {};
  float psum[2] = {};

  auto stage = [&](int kt, int buf) {
    unsigned short* Ks  = smem + buf * 4096;
    unsigned short* KTs = smem + 8192 + buf * 4096;
    // 512 threads x 16B = one 64x64 bf16 tile each, single pass
    int row = tid >> 3, g = (tid & 7) ^ (row & 7);
    GLOAD16(Kb + (size_t)(kt + row) * DH + g * 8,
            Ks + (size_t)wbase * 8);
    GLOAD16(KbT + (size_t)row * SEQ + kt + g * 8,
            KTs + (size_t)wbase * 8);
  };

  stage(0, 0);
  int buf = 0;
  for (int it = 0; it < SEQ / 64; ++it) {
    __syncthreads();
    if (it + 1 < SEQ / 64) stage((it + 1) * 64, buf ^ 1);
    const unsigned short* Ks  = smem + buf * 4096;
    const unsigned short* KTs = smem + 8192 + buf * 4096;

    // St[key][q] over this wave's 32-key half; A = K-frag, B = aq.
    floatx4 St[2][2] = {};
    __builtin_amdgcn_s_setprio(1);
#pragma unroll
    for (int kt = 0; kt < 2; ++kt) {
      int rb = (kh * 32 + kt * 16 + r16) * 64;
      bf16x8 k0 = *(const bf16x8*)&Ks[rb + ((quad) ^ rs) * 8];
      bf16x8 k1 = *(const bf16x8*)&Ks[rb + ((4 + quad) ^ rs) * 8];
#pragma unroll
      for (int nt = 0; nt < 2; ++nt) {
        St[kt][nt] = __builtin_amdgcn_mfma_f32_16x16x32_bf16(k0, aq[nt][0], St[kt][nt], 0, 0, 0);
        St[kt][nt] = __builtin_amdgcn_mfma_f32_16x16x32_bf16(k1, aq[nt][1], St[kt][nt], 0, 0, 0);
      }
    }
    __builtin_amdgcn_s_setprio(0);

    // P: lane holds keys kh*32+kt*16+quad*4+{0..3} for q = qw+nt*16+r16.
    // Disjoint Ps columns per key-half -> no cross-wave hazard.
#pragma unroll
    for (int nt = 0; nt < 2; ++nt) {
      float sc = scm[nt];
      int prow = (qw + nt * 16 + r16) * 68 + kh * 32 + quad * 4;
#pragma unroll
      for (int kt = 0; kt < 2; ++kt) {
        float p0 = __builtin_amdgcn_exp2f(St[kt][nt][0] * sc);
        float p1 = __builtin_amdgcn_exp2f(St[kt][nt][1] * sc);
        float p2 = __builtin_amdgcn_exp2f(St[kt][nt][2] * sc);
        float p3 = __builtin_amdgcn_exp2f(St[kt][nt][3] * sc);
        psum[nt] += (p0 + p1) + (p2 + p3);
        __hip_bfloat162 lo = __float22bfloat162_rn(make_float2(p0, p1));
        __hip_bfloat162 hi = __float22bfloat162_rn(make_float2(p2, p3));
        unsigned u0, u1;
        __builtin_memcpy(&u0, &lo, 4);
        __builtin_memcpy(&u1, &hi, 4);
        *(uint2*)&Ps[prow + kt * 16] = make_uint2(u0, u1);
      }
    }

    // O += P V over this wave's key-half (same-wave LDS RAW on Ps).
    bf16x8 ap[2];
#pragma unroll
    for (int mi = 0; mi < 2; ++mi)
      ap[mi] = *(const bf16x8*)&Ps[(qw + mi * 16 + r16) * 68 + kh * 32 + quad * 8];
    __builtin_amdgcn_s_setprio(1);
#pragma unroll
    for (int ni = 0; ni < 4; ++ni) {
      bf16x8 v = *(const bf16x8*)&KTs[(ni * 16 + r16) * 64 + ((kh * 4 + quad) ^ rs) * 8];
#pragma unroll
      for (int mi = 0; mi < 2; ++mi)
        accO[mi][ni] = __builtin_amdgcn_mfma_f32_16x16x32_bf16(ap[mi], v, accO[mi][ni], 0, 0, 0);
    }
    __builtin_amdgcn_s_setprio(0);
    buf ^= 1;
  }

  // ---- split-K epilogue: combine the two key-halves of each q-group ----
  // quad-reduce psum -> every lane holds its half's sum for q = qw+nt*16+r16
#pragma unroll
  for (int nt = 0; nt < 2; ++nt) {
    float s = psum[nt];
    s += __shfl_xor(s, 16);
    s += __shfl_xor(s, 32);
    psum[nt] = s;
  }
  __syncthreads();                       // all loop LDS reads drained
  float* r0 = (float*)&smem[25088];
  float* r1 = (float*)&smem[25344];
  float* Of = (float*)smem;              // [128][66] f32 (stride breaks banks)
  if (quad == 0) {
    float* rx = kh ? r1 : r0;
#pragma unroll
    for (int nt = 0; nt < 2; ++nt)
      rx[qw + nt * 16 + r16] = psum[nt];
  }
  if (kh == 1) {
#pragma unroll
    for (int mi = 0; mi < 2; ++mi)
#pragma unroll
      for (int ni = 0; ni < 4; ++ni)
#pragma unroll
        for (int r = 0; r < 4; ++r)
          Of[(qw + mi * 16 + quad * 4 + r) * 66 + ni * 16 + r16] = accO[mi][ni][r];
  }
  __syncthreads();
  if (kh == 0) {
    float rinv[2][4];
#pragma unroll
    for (int mi = 0; mi < 2; ++mi)
#pragma unroll
      for (int r = 0; r < 4; ++r) {
        int q = qw + mi * 16 + quad * 4 + r;
        rinv[mi][r] = 1.0f / (r0[q] + r1[q]);
      }
#pragma unroll
    for (int mi = 0; mi < 2; ++mi)
#pragma unroll
      for (int ni = 0; ni < 4; ++ni)
#pragma unroll
        for (int r = 0; r < 4; ++r) {
          int q = qw + mi * 16 + quad * 4 + r;
          float val = accO[mi][ni][r] + Of[q * 66 + ni * 16 + r16];
          int l = q0 + q;
          int col = h * DH + ni * 16 + r16;
          wV[(size_t)(b * SEQ + l) * DIM + col] = f2bf(val * rinv[mi][r]);
        }
  }
}

// ---------------- output projection: out = wV @ Wo^T + bo (fp32) -----------
__global__ __launch_bounds__(256) void proj_o_kernel(
    const unsigned short* __restrict__ wVb, const unsigned short* __restrict__ Wob,
    const float* __restrict__ bo, float* __restrict__ out)
{
  __shared__ __align__(16) unsigned short smem[24576];   // 48 KB
  const int tid = threadIdx.x;
  const int lane = tid & 63;
  const int w = tid >> 6;
  const int wr = w >> 1, wc = w & 1;
  const int quad = lane >> 4, r16 = lane & 15;
  const int rs = r16 & 7;
  const int m0 = blockIdx.x * 64, n0 = blockIdx.y * 128;
  const int wbase = (tid & ~63);

  floatx4 acc[2][4] = {};

  auto stage = [&](int kt, int buf) {
    unsigned short* As = smem + buf * 12288;
    unsigned short* Bs = As + 4096;
#pragma unroll
    for (int i = 0; i < 2; ++i) {
      int c = tid + i * 256;
      int row = c >> 3, g = (c & 7) ^ (row & 7);
      GLOAD16(wVb + (size_t)(m0 + row) * DIM + kt + g * 8,
              As + (size_t)(wbase + i * 256) * 8);
    }
#pragma unroll
    for (int i = 0; i < 4; ++i) {
      int c = tid + i * 256;
      int row = c >> 3, g = (c & 7) ^ (row & 7);
      GLOAD16(Wob + (size_t)(n0 + row) * DIM + kt + g * 8,
              Bs + (size_t)(wbase + i * 256) * 8);
    }
  };

  stage(0, 0);
  int buf = 0;
  for (int it = 0; it < 12; ++it) {
    __syncthreads();
    if (it + 1 < 12) stage((it + 1) * 64, buf ^ 1);
    const unsigned short* As = smem + buf * 12288;
    const unsigned short* Bs = As + 4096;
    bf16x8 af[2][2], bfm[4][2];
#pragma unroll
    for (int mi = 0; mi < 2; ++mi)
#pragma unroll
      for (int kc = 0; kc < 2; ++kc)
        af[mi][kc] = *(const bf16x8*)&As[(wr * 32 + mi * 16 + r16) * 64 + ((kc * 4 + quad) ^ rs) * 8];
#pragma unroll
    for (int ni = 0; ni < 4; ++ni)
#pragma unroll
      for (int kc = 0; kc < 2; ++kc)
        bfm[ni][kc] = *(const bf16x8*)&Bs[(wc * 64 + ni * 16 + r16) * 64 + ((kc * 4 + quad) ^ rs) * 8];
#pragma unroll
    for (int mi = 0; mi < 2; ++mi)
#pragma unroll
      for (int ni = 0; ni < 4; ++ni) {
        acc[mi][ni] = __builtin_amdgcn_mfma_f32_16x16x32_bf16(af[mi][0], bfm[ni][0], acc[mi][ni], 0, 0, 0);
        acc[mi][ni] = __builtin_amdgcn_mfma_f32_16x16x32_bf16(af[mi][1], bfm[ni][1], acc[mi][ni], 0, 0, 0);
      }
    buf ^= 1;
  }

#pragma unroll
  for (int mi = 0; mi < 2; ++mi)
#pragma unroll
    for (int ni = 0; ni < 4; ++ni) {
      int col = n0 + wc * 64 + ni * 16 + r16;
      float bias = bo[col];
#pragma unroll
      for (int r = 0; r < 4; ++r) {
        int row = m0 + wr * 32 + mi * 16 + quad * 4 + r;
        out[(size_t)row * DIM + col] = acc[mi][ni][r] + bias;
      }
    }
}

extern "C" void kernel_launch(void* const* d_in, const int* in_sizes, int n_in,
                              void* d_out, int out_size, void* d_ws, size_t ws_size,
                              hipStream_t stream) {
  // inputs: x, attention_mask, Wq, bq, Wk, bk, Wv, bv, Wo, bo  (Q dead; V==K)
  const float* x  = (const float*)d_in[0];
  const int* mask = (const int*)d_in[1];
  const float* Wk = (const float*)d_in[4];
  const float* bk = (const float*)d_in[5];
  const float* Wo = (const float*)d_in[8];
  const float* bo = (const float*)d_in[9];
  float* out = (float*)d_out;

  unsigned short* p = (unsigned short*)d_ws;
  unsigned short* xb   = p;  p += (size_t)8192 * 768;
  unsigned short* Wkb  = p;  p += (size_t)768 * 768;
  unsigned short* Wob  = p;  p += (size_t)768 * 768;
  unsigned short* Kbh  = p;  p += (size_t)NUM_B * NH * SEQ * DH;
  unsigned short* KbhT = p;  p += (size_t)NUM_B * NH * SEQ * DH;
  unsigned short* wVb  = p;  // [8192][768]

  convert_kernel<<<7296, 256, 0, stream>>>(x, Wk, Wo, xb, Wkb, Wob);
  proj_k_kernel<<<dim3(128, 6), 256, 0, stream>>>(xb, Wkb, bk, Kbh, KbhT);
  attn_kernel<<<768, 512, 0, stream>>>(Kbh, KbhT, mask, wVb);
  proj_o_kernel<<<dim3(128, 6), 256, 0, stream>>>(wVb, Wob, bo, out);
}

// Round 9
// 165.085 us; speedup vs baseline: 1.3365x; 1.0562x over previous
//
#include <hip/hip_runtime.h>
#include <hip/hip_bf16.h>

#define NUM_B 8
#define SEQ 1024
#define DIM 768
#define NH 12
#define DH 64

typedef __attribute__((ext_vector_type(8))) short bf16x8;
typedef __attribute__((ext_vector_type(4))) float floatx4;
typedef __attribute__((ext_vector_type(16))) float floatx16;
typedef __attribute__((ext_vector_type(4))) unsigned short ushortx4;
typedef __attribute__((ext_vector_type(8))) unsigned short ushortx8;

__device__ __forceinline__ unsigned short f2bf(float f) {
  unsigned u = __float_as_uint(f);
  u += 0x7FFFu + ((u >> 16) & 1u);   // round-to-nearest-even
  return (unsigned short)(u >> 16);
}

// async global->LDS, 16B per lane; LDS dest = wave-uniform base + lane*16
#define GLOAD16(g, l) __builtin_amdgcn_global_load_lds( \
    (const __attribute__((address_space(1))) unsigned int*)(g), \
    (__attribute__((address_space(3))) unsigned int*)(l), 16, 0, 0)

// ---------------- one-shot fp32 -> bf16 conversion (x, Wk, Wo) -------------
__global__ __launch_bounds__(256) void convert_kernel(
    const float* __restrict__ x, const float* __restrict__ Wk,
    const float* __restrict__ Wo, unsigned short* __restrict__ xb,
    unsigned short* __restrict__ Wkb, unsigned short* __restrict__ Wob)
{
  const int NX4 = (8192 * 768) / 4;
  const int NW4 = (768 * 768) / 4;
  int i = blockIdx.x * 256 + threadIdx.x;
  const float* s; unsigned short* d; int off;
  if (i < NX4)            { s = x;  d = xb;  off = i; }
  else if (i < NX4 + NW4) { s = Wk; d = Wkb; off = i - NX4; }
  else                    { s = Wo; d = Wob; off = i - NX4 - NW4; }
  float4 v = ((const float4*)s)[off];
  ushortx4 h;
  h.x = f2bf(v.x); h.y = f2bf(v.y); h.z = f2bf(v.z); h.w = f2bf(v.w);
  ((ushortx4*)d)[off] = h;
}

// ---------------- K projection + fused transpose ---------------------------
// 64(M) x 128(N), BK=64, dbuf swizzled global_load_lds, grid 768 (3/CU).
__global__ __launch_bounds__(256) void proj_k_kernel(
    const unsigned short* __restrict__ xb, const unsigned short* __restrict__ Wkb,
    const float* __restrict__ bk, unsigned short* __restrict__ Kbh,
    unsigned short* __restrict__ KbhT)
{
  __shared__ __align__(16) unsigned short smem[24576];   // 48 KB (2 x 24 KB)
  const int tid = threadIdx.x;
  const int lane = tid & 63;
  const int w = tid >> 6;
  const int wr = w >> 1, wc = w & 1;
  const int quad = lane >> 4, r16 = lane & 15;
  const int rs = r16 & 7;
  const int m0 = blockIdx.x * 64, n0 = blockIdx.y * 128;
  const int wbase = (tid & ~63);

  floatx4 acc[2][4] = {};

  auto stage = [&](int kt, int buf) {
    unsigned short* As = smem + buf * 12288;
    unsigned short* Bs = As + 4096;
#pragma unroll
    for (int i = 0; i < 2; ++i) {
      int c = tid + i * 256;
      int row = c >> 3, g = (c & 7) ^ (row & 7);
      GLOAD16(xb + (size_t)(m0 + row) * DIM + kt + g * 8,
              As + (size_t)(wbase + i * 256) * 8);
    }
#pragma unroll
    for (int i = 0; i < 4; ++i) {
      int c = tid + i * 256;
      int row = c >> 3, g = (c & 7) ^ (row & 7);
      GLOAD16(Wkb + (size_t)(n0 + row) * DIM + kt + g * 8,
              Bs + (size_t)(wbase + i * 256) * 8);
    }
  };

  stage(0, 0);
  int buf = 0;
  for (int it = 0; it < 12; ++it) {
    __syncthreads();
    if (it + 1 < 12) stage((it + 1) * 64, buf ^ 1);
    const unsigned short* As = smem + buf * 12288;
    const unsigned short* Bs = As + 4096;
    bf16x8 af[2][2], bfm[4][2];
#pragma unroll
    for (int mi = 0; mi < 2; ++mi)
#pragma unroll
      for (int kc = 0; kc < 2; ++kc)
        af[mi][kc] = *(const bf16x8*)&As[(wr * 32 + mi * 16 + r16) * 64 + ((kc * 4 + quad) ^ rs) * 8];
#pragma unroll
    for (int ni = 0; ni < 4; ++ni)
#pragma unroll
      for (int kc = 0; kc < 2; ++kc)
        bfm[ni][kc] = *(const bf16x8*)&Bs[(wc * 64 + ni * 16 + r16) * 64 + ((kc * 4 + quad) ^ rs) * 8];
#pragma unroll
    for (int mi = 0; mi < 2; ++mi)
#pragma unroll
      for (int ni = 0; ni < 4; ++ni) {
        acc[mi][ni] = __builtin_amdgcn_mfma_f32_16x16x32_bf16(af[mi][0], bfm[ni][0], acc[mi][ni], 0, 0, 0);
        acc[mi][ni] = __builtin_amdgcn_mfma_f32_16x16x32_bf16(af[mi][1], bfm[ni][1], acc[mi][ni], 0, 0, 0);
      }
    buf ^= 1;
  }

  __syncthreads();                       // reuse smem as Ct [128 n][72]
  unsigned short* Ct = smem;
  const int bb = m0 >> 10, l0 = m0 & 1023;
#pragma unroll
  for (int mi = 0; mi < 2; ++mi)
#pragma unroll
    for (int ni = 0; ni < 4; ++ni) {
      int col = n0 + wc * 64 + ni * 16 + r16;   // j = h*64+dh
      float bias = bk[col];
      int hh = col >> 6, dd = col & 63;
      ushortx4 pk;
#pragma unroll
      for (int r = 0; r < 4; ++r) {
        int mrow = wr * 32 + mi * 16 + quad * 4 + r;
        unsigned short us = f2bf(acc[mi][ni][r] + bias);
        Kbh[((size_t)(bb * NH + hh) * SEQ + l0 + mrow) * DH + dd] = us;
        pk[r] = us;
      }
      *(ushortx4*)&Ct[(wc * 64 + ni * 16 + r16) * 72 + wr * 32 + mi * 16 + quad * 4] = pk;
    }
  __syncthreads();
#pragma unroll
  for (int i = 0; i < 4; ++i) {
    int c = tid + i * 256;
    int row = c >> 3, ch = c & 7;
    ushortx8 v = *(const ushortx8*)&Ct[row * 72 + ch * 8];
    int j = n0 + row;
    int hh = j >> 6, dd = j & 63;
    *(ushortx8*)&KbhT[((size_t)(bb * NH + hh) * DH + dd) * SEQ + l0 + ch * 8] = v;
  }
}

// ---------------- fused attention ------------------------------------------
// 1-D grid 768 (3 blocks/CU, balanced), 256 threads = 4 waves x 32 q.
// RESTRUCTURE (m214 recipe, D=64): 32x32x16 MFMAs with SWAPPED QK^T.
// St = mfma(K_frag, Q_frag) -> C layout col=lane&31 (q), row=key
// (r&3)+8*(r>>2)+4*(lane>>5): each lane holds 16 keys of ONE q-column ->
// softmax is fully in-register (psum lane-local; one shfl_xor(32) at end).
// P -> PV B-operand: 8 cvt_pk + 4 shfl_xor(32) + 4 cndmask per 32-key
// group. DELETED: Ps LDS buffer + its ds_write->lgkm->ds_read RAW chain,
// rsum. MFMA instr count halves (16 vs 32 per 32q per tile); per-q K/V
// LDS reads halve. LDS 51.2 KB -> 32 KB.
// XCD decode: 8 q-tiles of each bh on one XCD (Lb%8==bh%8), K/KT L2-resident.
__global__ __launch_bounds__(256) void attn_kernel(
    const unsigned short* __restrict__ Kbh, const unsigned short* __restrict__ KbhT,
    const int* __restrict__ mask, unsigned short* __restrict__ wV)
{
  __shared__ __align__(16) unsigned short smem[16384];   // 32 KB: Ks/KTs dbuf

  const int tid = threadIdx.x;
  const int lane = tid & 63;
  const int w = tid >> 6;                // 0..3
  const int q = lane & 31;               // lane's q within the wave's 32-q tile
  const int hh = lane >> 5;              // half-wave (k-slot group)
  const int q7 = q & 7;                  // XOR swizzle key (row&7)
  // XCD-aware bijective decode (XCD = linear%8 round-robin assumption):
  const int Lb = blockIdx.x;
  const int qt = (Lb >> 3) & 7;
  const int bh = (Lb >> 6) * 8 + (Lb & 7);
  const int b = bh / NH, h = bh % NH;
  const unsigned short* Kb  = Kbh  + (size_t)bh * SEQ * DH;
  const unsigned short* KbT = KbhT + (size_t)bh * DH * SEQ;
  const int q0 = qt * 128;
  const int qw = w * 32;                 // wave's 32-q range within tile
  const int wbase = (tid & ~63);
  // 1/sqrt(768) * log2(e): exp(x*s) == exp2(x*s*log2e)
  const float SCALE2 = 0.036084391824351615f * 1.4426950408889634f;

  // mask folded into scale: masked row -> Q=0 -> St=0 -> p=1 (uniform softmax)
  const float scm = (mask[b * SEQ + q0 + qw + q] != 0) ? SCALE2 : 0.0f;

  // Q fragments, pre-scaled by scm (B-operand: col=q=lane&31, k=d=s*16+hh*8+j)
  bf16x8 aq[4];
#pragma unroll
  for (int s = 0; s < 4; ++s) {
    bf16x8 v = *(const bf16x8*)(Kb + (size_t)(q0 + qw + q) * DH + s * 16 + hh * 8);
    ushortx8 u; __builtin_memcpy(&u, &v, 16);
    ushortx8 o;
#pragma unroll
    for (int j = 0; j < 8; j += 2) {
      float f0 = __uint_as_float(((unsigned)u[j]) << 16) * scm;
      float f1 = __uint_as_float(((unsigned)u[j + 1]) << 16) * scm;
      __hip_bfloat162 hcv = __float22bfloat162_rn(make_float2(f0, f1));
      unsigned hu; __builtin_memcpy(&hu, &hcv, 4);
      o[j] = (unsigned short)(hu & 0xffffu);
      o[j + 1] = (unsigned short)(hu >> 16);
    }
    __builtin_memcpy(&aq[s], &o, 16);
  }

  floatx16 accO[2] = {};                 // O^T[d0*32+row][q], d0 = 0,1
  float psum = 0.0f;

  auto stage = [&](int kt, int buf) {
    unsigned short* Ks  = smem + buf * 4096;
    unsigned short* KTs = smem + 8192 + buf * 4096;
    // 256 threads x 16B x 2 passes per 64x64 bf16 tile
#pragma unroll
    for (int i = 0; i < 2; ++i) {
      int c = tid + i * 256;
      int row = c >> 3, g = (c & 7) ^ (row & 7);
      GLOAD16(Kb + (size_t)(kt + row) * DH + g * 8,
              Ks + (size_t)(wbase + i * 256) * 8);
    }
#pragma unroll
    for (int i = 0; i < 2; ++i) {
      int c = tid + i * 256;
      int row = c >> 3, g = (c & 7) ^ (row & 7);
      GLOAD16(KbT + (size_t)row * SEQ + kt + g * 8,
              KTs + (size_t)(wbase + i * 256) * 8);
    }
  };

  stage(0, 0);
  int buf = 0;
  for (int it = 0; it < SEQ / 64; ++it) {
    __syncthreads();
    if (it + 1 < SEQ / 64) stage((it + 1) * 64, buf ^ 1);
    const unsigned short* Ks  = smem + buf * 4096;
    const unsigned short* KTs = smem + 8192 + buf * 4096;

    bf16x8 pa[4];                        // PV B-frags: key steps s=0..3

#pragma unroll
    for (int kt = 0; kt < 2; ++kt) {
      // St[key][q] over 32 keys: A = K-frag (row=key=kt*32+q', k=d), B = aq
      floatx16 St = {};
      __builtin_amdgcn_s_setprio(1);
#pragma unroll
      for (int s = 0; s < 4; ++s) {
        bf16x8 kf = *(const bf16x8*)&Ks[(kt * 32 + q) * 64 + ((2 * s + hh) ^ q7) * 8];
        St = __builtin_amdgcn_mfma_f32_32x32x16_bf16(kf, aq[s], St, 0, 0, 0);
      }
      __builtin_amdgcn_s_setprio(0);

      // softmax partials in-register; pack pairs to bf16.
      // reg r -> key kt*32 + (r&3)+8*(r>>2)+4*hh
      unsigned pk[8];
#pragma unroll
      for (int j = 0; j < 8; ++j) {
        float pa_ = __builtin_amdgcn_exp2f(St[2 * j]);
        float pb_ = __builtin_amdgcn_exp2f(St[2 * j + 1]);
        psum += pa_ + pb_;
        __hip_bfloat162 hcv = __float22bfloat162_rn(make_float2(pa_, pb_));
        __builtin_memcpy(&pk[j], &hcv, 4);
      }
      // cross-half exchange (partner lane = lane^32 holds the other 16 keys)
      unsigned x0 = (unsigned)__shfl_xor((int)pk[0], 32);
      unsigned x1 = (unsigned)__shfl_xor((int)pk[1], 32);
      unsigned x2 = (unsigned)__shfl_xor((int)pk[2], 32);
      unsigned x3 = (unsigned)__shfl_xor((int)pk[3], 32);
      unsigned x4 = (unsigned)__shfl_xor((int)pk[4], 32);
      unsigned x5 = (unsigned)__shfl_xor((int)pk[5], 32);
      unsigned x6 = (unsigned)__shfl_xor((int)pk[6], 32);
      unsigned x7 = (unsigned)__shfl_xor((int)pk[7], 32);
      // B-frag (col=q, k=key= s*16 + hh*8 + j):
      uint4 B0 = make_uint4(hh ? x2 : pk[0], hh ? x3 : pk[1],
                            hh ? pk[2] : x0, hh ? pk[3] : x1);
      uint4 B1 = make_uint4(hh ? x6 : pk[4], hh ? x7 : pk[5],
                            hh ? pk[6] : x4, hh ? pk[7] : x5);
      __builtin_memcpy(&pa[kt * 2 + 0], &B0, 16);
      __builtin_memcpy(&pa[kt * 2 + 1], &B1, 16);
    }

    // O^T[d][q] += V^T[d][key] P^T[key][q]; A = V^T-frag from KTs
    __builtin_amdgcn_s_setprio(1);
#pragma unroll
    for (int d0 = 0; d0 < 2; ++d0)
#pragma unroll
      for (int s = 0; s < 4; ++s) {
        bf16x8 vf = *(const bf16x8*)&KTs[(d0 * 32 + q) * 64 + ((2 * s + hh) ^ q7) * 8];
        accO[d0] = __builtin_amdgcn_mfma_f32_32x32x16_bf16(vf, pa[s], accO[d0], 0, 0, 0);
      }
    __builtin_amdgcn_s_setprio(0);
    buf ^= 1;
  }

  // lane holds sums over its 16-key half (all tiles); partner has the rest.
  psum += __shfl_xor(psum, 32);
  float rinv = 1.0f / psum;

  // accO C-layout: col=q (this lane's q), row d = (r&3)+8*(r>>2)+4*hh
  const size_t orow = (size_t)(b * SEQ + q0 + qw + q) * DIM + h * DH;
#pragma unroll
  for (int d0 = 0; d0 < 2; ++d0)
#pragma unroll
    for (int rg = 0; rg < 4; ++rg) {
      ushortx4 st;
#pragma unroll
      for (int i = 0; i < 4; ++i)
        st[i] = f2bf(accO[d0][rg * 4 + i] * rinv);
      *(ushortx4*)&wV[orow + d0 * 32 + rg * 8 + hh * 4] = st;
    }
}

// ---------------- output projection: out = wV @ Wo^T + bo (fp32) -----------
__global__ __launch_bounds__(256) void proj_o_kernel(
    const unsigned short* __restrict__ wVb, const unsigned short* __restrict__ Wob,
    const float* __restrict__ bo, float* __restrict__ out)
{
  __shared__ __align__(16) unsigned short smem[24576];   // 48 KB
  const int tid = threadIdx.x;
  const int lane = tid & 63;
  const int w = tid >> 6;
  const int wr = w >> 1, wc = w & 1;
  const int quad = lane >> 4, r16 = lane & 15;
  const int rs = r16 & 7;
  const int m0 = blockIdx.x * 64, n0 = blockIdx.y * 128;
  const int wbase = (tid & ~63);

  floatx4 acc[2][4] = {};

  auto stage = [&](int kt, int buf) {
    unsigned short* As = smem + buf * 12288;
    unsigned short* Bs = As + 4096;
#pragma unroll
    for (int i = 0; i < 2; ++i) {
      int c = tid + i * 256;
      int row = c >> 3, g = (c & 7) ^ (row & 7);
      GLOAD16(wVb + (size_t)(m0 + row) * DIM + kt + g * 8,
              As + (size_t)(wbase + i * 256) * 8);
    }
#pragma unroll
    for (int i = 0; i < 4; ++i) {
      int c = tid + i * 256;
      int row = c >> 3, g = (c & 7) ^ (row & 7);
      GLOAD16(Wob + (size_t)(n0 + row) * DIM + kt + g * 8,
              Bs + (size_t)(wbase + i * 256) * 8);
    }
  };

  stage(0, 0);
  int buf = 0;
  for (int it = 0; it < 12; ++it) {
    __syncthreads();
    if (it + 1 < 12) stage((it + 1) * 64, buf ^ 1);
    const unsigned short* As = smem + buf * 12288;
    const unsigned short* Bs = As + 4096;
    bf16x8 af[2][2], bfm[4][2];
#pragma unroll
    for (int mi = 0; mi < 2; ++mi)
#pragma unroll
      for (int kc = 0; kc < 2; ++kc)
        af[mi][kc] = *(const bf16x8*)&As[(wr * 32 + mi * 16 + r16) * 64 + ((kc * 4 + quad) ^ rs) * 8];
#pragma unroll
    for (int ni = 0; ni < 4; ++ni)
#pragma unroll
      for (int kc = 0; kc < 2; ++kc)
        bfm[ni][kc] = *(const bf16x8*)&Bs[(wc * 64 + ni * 16 + r16) * 64 + ((kc * 4 + quad) ^ rs) * 8];
#pragma unroll
    for (int mi = 0; mi < 2; ++mi)
#pragma unroll
      for (int ni = 0; ni < 4; ++ni) {
        acc[mi][ni] = __builtin_amdgcn_mfma_f32_16x16x32_bf16(af[mi][0], bfm[ni][0], acc[mi][ni], 0, 0, 0);
        acc[mi][ni] = __builtin_amdgcn_mfma_f32_16x16x32_bf16(af[mi][1], bfm[ni][1], acc[mi][ni], 0, 0, 0);
      }
    buf ^= 1;
  }

#pragma unroll
  for (int mi = 0; mi < 2; ++mi)
#pragma unroll
    for (int ni = 0; ni < 4; ++ni) {
      int col = n0 + wc * 64 + ni * 16 + r16;
      float bias = bo[col];
#pragma unroll
      for (int r = 0; r < 4; ++r) {
        int row = m0 + wr * 32 + mi * 16 + quad * 4 + r;
        out[(size_t)row * DIM + col] = acc[mi][ni][r] + bias;
      }
    }
}

extern "C" void kernel_launch(void* const* d_in, const int* in_sizes, int n_in,
                              void* d_out, int out_size, void* d_ws, size_t ws_size,
                              hipStream_t stream) {
  // inputs: x, attention_mask, Wq, bq, Wk, bk, Wv, bv, Wo, bo  (Q dead; V==K)
  const float* x  = (const float*)d_in[0];
  const int* mask = (const int*)d_in[1];
  const float* Wk = (const float*)d_in[4];
  const float* bk = (const float*)d_in[5];
  const float* Wo = (const float*)d_in[8];
  const float* bo = (const float*)d_in[9];
  float* out = (float*)d_out;

  unsigned short* p = (unsigned short*)d_ws;
  unsigned short* xb   = p;  p += (size_t)8192 * 768;
  unsigned short* Wkb  = p;  p += (size_t)768 * 768;
  unsigned short* Wob  = p;  p += (size_t)768 * 768;
  unsigned short* Kbh  = p;  p += (size_t)NUM_B * NH * SEQ * DH;
  unsigned short* KbhT = p;  p += (size_t)NUM_B * NH * SEQ * DH;
  unsigned short* wVb  = p;  // [8192][768]

  convert_kernel<<<7296, 256, 0, stream>>>(x, Wk, Wo, xb, Wkb, Wob);
  proj_k_kernel<<<dim3(128, 6), 256, 0, stream>>>(xb, Wkb, bk, Kbh, KbhT);
  attn_kernel<<<768, 256, 0, stream>>>(Kbh, KbhT, mask, wVb);
  proj_o_kernel<<<dim3(128, 6), 256, 0, stream>>>(wVb, Wob, bo, out);
}